// Round 11
// baseline (159.683 us; speedup 1.0000x reference)
//
#include <hip/hip_runtime.h>
#include <stdint.h>

// Problem constants
#define B_   2
#define S_   2048
#define D_   768
#define H_   12
#define DH_  64
#define N3_  2304   // 3*D
#define M_   4096   // B*S

typedef __attribute__((ext_vector_type(8))) short    bf16x8;
typedef __attribute__((ext_vector_type(4))) float    f32x4;
typedef __attribute__((ext_vector_type(4))) int      i32x4;
typedef __attribute__((ext_vector_type(4))) unsigned short u16x4;
typedef _Float16 f16x4 __attribute__((ext_vector_type(4)));
typedef __fp16   h16x2 __attribute__((ext_vector_type(2)));   // cvt_pkrtz result type

// fold 1/sqrt(dh) * log2(e) into K at write time -> scores exit MFMA in exp2 domain
#define KSCALE 0.18033688011112042f
#define LSTRIDE (24 * S_)                 // l-buffer stride per split-K half
#define ONE_EL  ((size_t)24 * S_ * DH_)   // elements per Onum partial buffer

__device__ inline unsigned short f2bf(float f) {
    union { float f; unsigned u; } v; v.f = f;
    unsigned r = v.u + 0x7FFFu + ((v.u >> 16) & 1u);   // RNE
    return (unsigned short)(r >> 16);
}

// async 16B global -> LDS (DMA; LDS dest = wave-uniform base + lane*16)
__device__ inline void async_copy16(const void* g, void* l) {
    __builtin_amdgcn_global_load_lds((const __attribute__((address_space(1))) void*)g,
                                     (__attribute__((address_space(3))) void*)l, 16, 0, 0);
}

// ---------------------------------------------------------------------------
// Fused prep: x->bf16 (blocks 0..3071), w_in transpose (3072..4799),
// w_out transpose (4800..5375). Branch is block-uniform.
__global__ __launch_bounds__(256) void prep_all(
    const float* __restrict__ x, const float* __restrict__ w_in,
    const float* __restrict__ w_out,
    unsigned short* __restrict__ xb, unsigned short* __restrict__ winT,
    unsigned short* __restrict__ woutT)
{
    __shared__ unsigned short t[32][33];
    const int gid = blockIdx.x, tid = threadIdx.x;
    if (gid < 3072) {                      // cvt: 3072*256*4 = M*D elements
        int i = gid * 256 + tid;
        f32x4 v = *(const f32x4*)(x + (size_t)i * 4);
        u16x4 o;
        o.x = f2bf(v.x); o.y = f2bf(v.y); o.z = f2bf(v.z); o.w = f2bf(v.w);
        *(u16x4*)(xb + (size_t)i * 4) = o;
        return;
    }
    const float* src; unsigned short* dst; int R, C, bx, by;
    if (gid < 4800) { int b = gid - 3072; src = w_in;  dst = winT;  R = D_; C = N3_; bx = b % 72; by = b / 72; }
    else            { int b = gid - 4800; src = w_out; dst = woutT; R = D_; C = D_;  bx = b % 24; by = b / 24; }
    int c0 = bx * 32, r0 = by * 32, tx = tid & 31, ty = tid >> 5;
#pragma unroll
    for (int j = 0; j < 4; j++)
        t[ty + j * 8][tx] = f2bf(src[(size_t)(r0 + ty + j * 8) * C + c0 + tx]);
    __syncthreads();
#pragma unroll
    for (int j = 0; j < 4; j++)
        dst[(size_t)(c0 + ty + j * 8) * R + r0 + tx] = t[tx][ty + j * 8];
}

// ---------------------------------------------------------------------------
// GEMM1: QKV projection (R4-proven best). Tile 128x96, BK=64, XOR-swizzled
// LDS rows (chunk^=(row&7)) via pre-swizzled global source; 2 barriers/iter,
// 12 iters. 1-D grid 768 = exactly 3 blocks/CU with XCD-affinity swizzle.
__global__ __launch_bounds__(256) void gemm_qkv(
    const unsigned short* __restrict__ A,
    const unsigned short* __restrict__ Bt,
    const float* __restrict__ bias,
    unsigned short* __restrict__ QK,
    unsigned short* __restrict__ Vt)
{
    __shared__ __align__(16) short Al[128 * 64];   // 16 KB
    __shared__ __align__(16) short Bl[96 * 64];    // 12 KB

    const int tid  = threadIdx.x;
    const int w    = tid >> 6;
    const int lane = tid & 63;
    const int r    = lane & 15;
    const int quad = lane >> 4;
    // swizzle: xcd = bid&7; m-tile = xcd + 8*(rest/24); n-tile = rest%24
    const int bid  = blockIdx.x;
    const int rest = bid >> 3;
    const int m0   = ((bid & 7) + 8 * (rest / 24)) * 128;
    const int n0   = (rest % 24) * 96;
    const int wm   = (w & 1) * 64;
    const int wn   = (w >> 1) * 48;
    const int K    = D_;

    f32x4 acc[4][3];
#pragma unroll
    for (int i = 0; i < 4; i++)
#pragma unroll
        for (int j = 0; j < 3; j++) acc[i][j] = f32x4{0.f, 0.f, 0.f, 0.f};

    // staging slots: slot c = tid + 256*j; row=c>>3, chunk=c&7; global chunk
    // g = chunk^(row&7) (pre-swizzle so LDS[row][chunk] = global chunk g).
    size_t ga[4], gb[3];
#pragma unroll
    for (int j = 0; j < 4; j++) {
        int c = tid + 256 * j, row = c >> 3, ch = c & 7, g = ch ^ (row & 7);
        ga[j] = (size_t)(m0 + row) * K + g * 8;
    }
#pragma unroll
    for (int j = 0; j < 3; j++) {
        int c = tid + 256 * j, row = c >> 3, ch = c & 7, g = ch ^ (row & 7);
        gb[j] = (size_t)(n0 + row) * K + g * 8;
    }

    for (int k0 = 0; k0 < K; k0 += 64) {
        __syncthreads();
#pragma unroll
        for (int j = 0; j < 4; j++)
            async_copy16(A + ga[j] + k0, &Al[(j * 256 + w * 64) * 8]);
#pragma unroll
        for (int j = 0; j < 3; j++)
            async_copy16(Bt + gb[j] + k0, &Bl[(j * 256 + w * 64) * 8]);
        __syncthreads();

#pragma unroll
        for (int kk = 0; kk < 2; kk++) {
            bf16x8 af[4], bf[3];
#pragma unroll
            for (int mi = 0; mi < 4; mi++)
                af[mi] = *(const bf16x8*)&Al[(wm + mi * 16 + r) * 64 +
                                             ((kk * 4 + quad) ^ (r & 7)) * 8];
#pragma unroll
            for (int ni = 0; ni < 3; ni++)
                bf[ni] = *(const bf16x8*)&Bl[(wn + ni * 16 + r) * 64 +
                                             ((kk * 4 + quad) ^ (r & 7)) * 8];
#pragma unroll
            for (int mi = 0; mi < 4; mi++)
#pragma unroll
                for (int ni = 0; ni < 3; ni++)
                    acc[mi][ni] = __builtin_amdgcn_mfma_f32_16x16x32_bf16(
                        af[mi], bf[ni], acc[mi][ni], 0, 0, 0);
        }
    }

    const size_t one = (size_t)B_ * H_ * S_ * DH_;
#pragma unroll
    for (int ni = 0; ni < 3; ni++) {
        int col  = n0 + wn + ni * 16 + r;        // 0..2303 (tiles never straddle parts)
        float bv = bias[col];
        int part = col / 768;                    // 0=q 1=k 2=v
        int cc   = col - part * 768;
        int h    = cc >> 6;
        int d    = cc & 63;
        if (part == 2) {
            // V^T direct: rows i=0..3 are consecutive s -> one 8B f16 pack
#pragma unroll
            for (int mi = 0; mi < 4; mi++) {
                int row0 = m0 + wm + mi * 16 + quad * 4;    // i=0; same b for i=0..3
                int b    = row0 >> 11;
                int s0   = row0 & 2047;
                u16x4 pk;
#pragma unroll
                for (int i = 0; i < 4; i++) {
                    union { _Float16 h; unsigned short s; } cv;
                    cv.h = (_Float16)(acc[mi][ni][i] + bv);
                    pk[i] = cv.s;
                }
                *(u16x4*)&Vt[(((size_t)(b * H_ + h)) * DH_ + d) * S_ + s0] = pk;
            }
        } else {
            float scl = (part == 1) ? KSCALE : 1.0f;
            unsigned short* dst = QK + (size_t)part * one;
#pragma unroll
            for (int mi = 0; mi < 4; mi++) {
#pragma unroll
                for (int i = 0; i < 4; i++) {
                    int row = m0 + wm + mi * 16 + quad * 4 + i;  // = b*S + s
                    int b   = row >> 11;
                    int s   = row & 2047;
                    dst[(((size_t)(b * H_ + h)) * S_ + s) * DH_ + d] =
                        f2bf((acc[mi][ni][i] + bv) * scl);
                }
            }
        }
    }
}

// ---------------------------------------------------------------------------
// GEMM2 FUSED with combine (R8-proven): out-projection with
// A = (O0+O1)/(l0+l1) computed during A-staging. k-tiles align with heads
// (BK=64=DH). A reg-staged (T14); B via global_load_lds DMA. Double-buffered,
// ONE barrier/iter. XOR-swizzled LDS. XCD swizzle. Grid 768.
__global__ __launch_bounds__(256) void gemm_out(
    const unsigned short* __restrict__ On,   // 2 contiguous f16 partials
    const float* __restrict__ lbuf,          // 2 x [bh*s] f32
    const unsigned short* __restrict__ Bt,   // woutT
    const float* __restrict__ bias,
    float* __restrict__ Cf)
{
    __shared__ __align__(16) short Al[2][64 * 64];   // 16 KB
    __shared__ __align__(16) short Bl[2][64 * 64];   // 16 KB

    const int tid  = threadIdx.x;
    const int w    = tid >> 6;
    const int lane = tid & 63;
    const int r    = lane & 15;
    const int quad = lane >> 4;
    const int bid  = blockIdx.x;
    const int rest = bid >> 3;
    const int m0   = ((bid & 7) + 8 * (rest / 12)) * 64;
    const int n0   = (rest % 12) * 64;
    const int wm   = (w & 1) * 32;
    const int wn   = (w >> 1) * 32;
    const int K    = D_;
    const int N    = D_;

    f32x4 acc[2][2];
#pragma unroll
    for (int i = 0; i < 2; i++)
#pragma unroll
        for (int j = 0; j < 2; j++) acc[i][j] = f32x4{0.f, 0.f, 0.f, 0.f};

    size_t abase[2]; int lrow0[2];
    size_t gb[2];
#pragma unroll
    for (int j = 0; j < 2; j++) {
        int c = tid + 256 * j, row = c >> 3, ch = c & 7, g = ch ^ (row & 7);
        int m = m0 + row, b = m >> 11, s = m & 2047;
        lrow0[j] = b * (H_ * S_) + s;
        abase[j] = (size_t)lrow0[j] * 64 + g * 8;
        gb[j] = (size_t)(n0 + row) * K + g * 8;
    }

    auto a_write = [&](int buf, const i32x4* a0, const i32x4* a1,
                       const float* l0, const float* l1) {
#pragma unroll
        for (int j = 0; j < 2; j++) {
            float inv = 1.0f / (l0[j] + l1[j]);
            const _Float16* f0 = (const _Float16*)&a0[j];
            const _Float16* f1 = (const _Float16*)&a1[j];
            unsigned short t8[8];
#pragma unroll
            for (int e = 0; e < 8; e++)
                t8[e] = f2bf(((float)f0[e] + (float)f1[e]) * inv);
            *(i32x4*)&Al[buf][(tid + 256 * j) * 8] = *(const i32x4*)t8;
        }
    };

    // prologue: stage tile 0 (head 0) into buf 0
    i32x4 a0[2], a1[2]; float l0[2], l1[2];
#pragma unroll
    for (int j = 0; j < 2; j++) {
        a0[j] = *(const i32x4*)&On[abase[j]];
        a1[j] = *(const i32x4*)&On[abase[j] + ONE_EL];
        l0[j] = lbuf[lrow0[j]];
        l1[j] = lbuf[LSTRIDE + lrow0[j]];
        async_copy16(Bt + gb[j], &Bl[0][(j * 256 + w * 64) * 8]);
    }
    a_write(0, a0, a1, l0, l1);
    __syncthreads();

    for (int it = 0; it < 12; it++) {
        const int cur = it & 1;
        if (it < 11) {
            const int itn = it + 1;
#pragma unroll
            for (int j = 0; j < 2; j++) {
                a0[j] = *(const i32x4*)&On[abase[j] + (size_t)itn * 131072];
                a1[j] = *(const i32x4*)&On[abase[j] + (size_t)itn * 131072 + ONE_EL];
                l0[j] = lbuf[lrow0[j] + itn * S_];
                l1[j] = lbuf[LSTRIDE + lrow0[j] + itn * S_];
                async_copy16(Bt + gb[j] + itn * 64, &Bl[cur ^ 1][(j * 256 + w * 64) * 8]);
            }
        }
#pragma unroll
        for (int kk = 0; kk < 2; kk++) {
            bf16x8 af[2], bf[2];
#pragma unroll
            for (int mi = 0; mi < 2; mi++)
                af[mi] = *(const bf16x8*)&Al[cur][(wm + mi * 16 + r) * 64 +
                                                  ((kk * 4 + quad) ^ (r & 7)) * 8];
#pragma unroll
            for (int ni = 0; ni < 2; ni++)
                bf[ni] = *(const bf16x8*)&Bl[cur][(wn + ni * 16 + r) * 64 +
                                                  ((kk * 4 + quad) ^ (r & 7)) * 8];
#pragma unroll
            for (int mi = 0; mi < 2; mi++)
#pragma unroll
                for (int ni = 0; ni < 2; ni++)
                    acc[mi][ni] = __builtin_amdgcn_mfma_f32_16x16x32_bf16(
                        af[mi], bf[ni], acc[mi][ni], 0, 0, 0);
        }
        if (it < 11) a_write(cur ^ 1, a0, a1, l0, l1);
        __syncthreads();
    }

#pragma unroll
    for (int ni = 0; ni < 2; ni++) {
        int col  = n0 + wn + ni * 16 + r;
        float bv = bias[col];
#pragma unroll
        for (int mi = 0; mi < 2; mi++) {
#pragma unroll
            for (int i = 0; i < 4; i++) {
                int row = m0 + wm + mi * 16 + quad * 4 + i;
                Cf[(size_t)row * N + col] = acc[mi][ni][i] + bv;
            }
        }
    }
}

// ---------------------------------------------------------------------------
// Flash attention v6 + T5 setprio (only change vs R10): s_setprio(1) wraps
// the QK^T and PV MFMA clusters. 3 independent blocks/CU at uncorrelated
// kt-iters -> scheduler can favor MFMA-entering waves over other blocks'
// staging waves (m191 attn precedent +4-7%). Everything else VERBATIM.
__global__ __launch_bounds__(256) void attn_kernel(
    const unsigned short* __restrict__ Q,
    const unsigned short* __restrict__ K,
    const unsigned short* __restrict__ Vt,
    unsigned short* __restrict__ On,
    float* __restrict__ lbuf)
{
    __shared__ __align__(16) short Kl[64 * 64];      // [key][dh], chunk^=(row&7)
    __shared__ __align__(16) short Vl[64 * 64];      // [dh][key], chunk^=(row&7)

    const int tid  = threadIdx.x;
    const int w    = tid >> 6;
    const int lane = tid & 63;
    const int r    = lane & 15;
    const int quad = lane >> 4;
    const int xk   = r & 7;
    const int bid  = blockIdx.x;
    const int bh   = bid % 24;            // head-major -> L2 locality
    const int t2   = bid / 24;            // 0..31
    const int qb   = t2 & 15;
    const int half = t2 >> 4;
    const size_t baseQK = (size_t)bh * S_ * DH_;
    const size_t baseV  = (size_t)bh * DH_ * S_;
    const int q0   = qb * 128;
    const int kt0  = half * 16;

    bf16x8 qf[2][2];
#pragma unroll
    for (int qt = 0; qt < 2; qt++) {
        const unsigned short* qp =
            Q + baseQK + (size_t)(q0 + w * 32 + qt * 16 + r) * DH_ + quad * 8;
        qf[qt][0] = *(const bf16x8*)(qp);
        qf[qt][1] = *(const bf16x8*)(qp + 32);
    }

    f32x4 o[2][4];
    f32x4 lacc[2];
#pragma unroll
    for (int qt = 0; qt < 2; qt++) {
        lacc[qt] = f32x4{0.f, 0.f, 0.f, 0.f};
#pragma unroll
        for (int nb = 0; nb < 4; nb++) o[qt][nb] = f32x4{0.f, 0.f, 0.f, 0.f};
    }

    const f16x4 ONES = {(_Float16)1.f, (_Float16)1.f, (_Float16)1.f, (_Float16)1.f};

    const int srw = tid >> 3, schk = tid & 7;
    const unsigned short* kg = K  + baseQK + (size_t)kt0 * 4096 + tid * 8;
    const unsigned short* vg = Vt + baseV + (size_t)kt0 * 64 + (size_t)srw * S_ + schk * 8;
    const int lb = srw * 64 + (schk ^ (srw & 7)) * 8;

    i32x4 kreg[2], vreg[2];
    kreg[0] = *(const i32x4*)(kg);
    kreg[1] = *(const i32x4*)(kg + 2048);
    vreg[0] = *(const i32x4*)(vg);
    vreg[1] = *(const i32x4*)(vg + 32 * S_);

    for (int it = 0; it < 16; it++) {
        __syncthreads();
        *(i32x4*)&Kl[lb]        = kreg[0];
        *(i32x4*)&Kl[lb + 2048] = kreg[1];
        *(i32x4*)&Vl[lb]        = vreg[0];
        *(i32x4*)&Vl[lb + 2048] = vreg[1];
        __syncthreads();

        if (it != 15) {
            const unsigned short* kn = kg + (it + 1) * 4096;
            const unsigned short* vn = vg + (it + 1) * 64;
            kreg[0] = *(const i32x4*)(kn);
            kreg[1] = *(const i32x4*)(kn + 2048);
            vreg[0] = *(const i32x4*)(vn);
            vreg[1] = *(const i32x4*)(vn + 32 * S_);
        }

        // S^T = K Q^T  (exp2 domain; KSCALE folded into K)
        f32x4 sa[2][4];
#pragma unroll
        for (int qt = 0; qt < 2; qt++)
#pragma unroll
            for (int kb = 0; kb < 4; kb++) sa[qt][kb] = f32x4{0.f, 0.f, 0.f, 0.f};
        __builtin_amdgcn_s_setprio(1);
#pragma unroll
        for (int t = 0; t < 2; t++)
#pragma unroll
            for (int kb = 0; kb < 4; kb++) {
                bf16x8 kf = *(const bf16x8*)&Kl[(kb * 16 + r) * 64 + ((t * 4 + quad) ^ xk) * 8];
#pragma unroll
                for (int qt = 0; qt < 2; qt++)
                    sa[qt][kb] = __builtin_amdgcn_mfma_f32_16x16x32_bf16(
                        kf, qf[qt][t], sa[qt][kb], 0, 0, 0);
            }
        __builtin_amdgcn_s_setprio(0);

        // p = exp2(s) -> f16 A-frags (layout already matches; cvt_pkrtz = RTZ)
        f16x4 pf[2][4];
#pragma unroll
        for (int qt = 0; qt < 2; qt++)
#pragma unroll
            for (int kb = 0; kb < 4; kb++) {
                float p0 = __builtin_amdgcn_exp2f(sa[qt][kb][0]);
                float p1 = __builtin_amdgcn_exp2f(sa[qt][kb][1]);
                float p2 = __builtin_amdgcn_exp2f(sa[qt][kb][2]);
                float p3 = __builtin_amdgcn_exp2f(sa[qt][kb][3]);
                union { f16x4 v; h16x2 h[2]; } u;
                u.h[0] = __builtin_amdgcn_cvt_pkrtz(p0, p1);
                u.h[1] = __builtin_amdgcn_cvt_pkrtz(p2, p3);
                pf[qt][kb] = u.v;
            }

        // O += P V  and  l += P 1   (fp16 MFMA, K=16 per kb)
        __builtin_amdgcn_s_setprio(1);
#pragma unroll
        for (int kb = 0; kb < 4; kb++) {
#pragma unroll
            for (int nb = 0; nb < 4; nb++) {
                f16x4 vf = *(const f16x4*)&Vl[(nb * 16 + r) * 64 +
                                              ((kb * 2 + (quad >> 1)) ^ xk) * 8 + (quad & 1) * 4];
#pragma unroll
                for (int qt = 0; qt < 2; qt++)
                    o[qt][nb] = __builtin_amdgcn_mfma_f32_16x16x16f16(
                        pf[qt][kb], vf, o[qt][nb], 0, 0, 0);
            }
#pragma unroll
            for (int qt = 0; qt < 2; qt++)
                lacc[qt] = __builtin_amdgcn_mfma_f32_16x16x16f16(
                    pf[qt][kb], ONES, lacc[qt], 0, 0, 0);
        }
        __builtin_amdgcn_s_setprio(0);
    }

    // epilogue: store UN-normalized partials (f16) + l (f32)
    unsigned short* Ob = On + (size_t)half * ONE_EL;
#pragma unroll
    for (int qt = 0; qt < 2; qt++)
#pragma unroll
        for (int i = 0; i < 4; i++) {
            int s = q0 + w * 32 + qt * 16 + quad * 4 + i;
            size_t row = (size_t)bh * S_ + s;
            if (r == 0) lbuf[half * LSTRIDE + row] = lacc[qt][i];
#pragma unroll
            for (int nb = 0; nb < 4; nb++) {
                union { _Float16 h; unsigned short u; } cv;
                cv.h = (_Float16)o[qt][nb][i];
                Ob[row * 64 + nb * 16 + r] = cv.u;
            }
        }
}

// ---------------------------------------------------------------------------
extern "C" void kernel_launch(void* const* d_in, const int* in_sizes, int n_in,
                              void* d_out, int out_size, void* d_ws, size_t ws_size,
                              hipStream_t stream) {
    const float* x     = (const float*)d_in[0];
    const float* w_in  = (const float*)d_in[1];
    const float* b_in  = (const float*)d_in[2];
    const float* w_out = (const float*)d_in[3];
    const float* b_out = (const float*)d_in[4];
    float* out = (float*)d_out;
    char* ws = (char*)d_ws;

    // workspace layout (bytes), ~48.8 MB:
    //   [0,        6291456)  xb (x bf16)
    //   [6291456,  9830400)  winT (bf16)   -> lbuf (f32, 393KB) after gemm_qkv
    //   [9830400, 11010048)  woutT (bf16)
    //   [11010048,17301504)  Q  (bf16)
    //   [17301504,23592960)  K  (bf16, scaled)
    //   [23592960,29884416)  Vt (fp16, written transposed by gemm_qkv)
    //   [36175872,48758784)  Onum: 2 contiguous f16 partials (2 x 6291456)
    unsigned short* xb    = (unsigned short*)(ws);
    unsigned short* winT  = (unsigned short*)(ws + 6291456);
    unsigned short* woutT = (unsigned short*)(ws + 9830400);
    unsigned short* QKV   = (unsigned short*)(ws + 11010048);
    unsigned short* On    = (unsigned short*)(ws + 36175872);

    const size_t one = (size_t)B_ * H_ * S_ * DH_;
    unsigned short* Vtbuf = QKV + 2 * one;
    float*          lbuf  = (float*)winT;             // winT dead after gemm_qkv

    prep_all<<<5376, 256, 0, stream>>>(x, w_in, w_out, xb, winT, woutT);

    gemm_qkv<<<768, 256, 0, stream>>>(xb, winT, b_in, QKV, Vtbuf);

    attn_kernel<<<24 * 16 * 2, 256, 0, stream>>>(
        QKV, QKV + one, Vtbuf, On, lbuf);

    gemm_out<<<768, 256, 0, stream>>>(On, lbuf, woutT, b_out, out);
}

// Round 12
// 151.538 us; speedup vs baseline: 1.0537x; 1.0537x over previous
//
#include <hip/hip_runtime.h>
#include <stdint.h>

// Problem constants
#define B_   2
#define S_   2048
#define D_   768
#define H_   12
#define DH_  64
#define N3_  2304   // 3*D
#define M_   4096   // B*S

typedef __attribute__((ext_vector_type(8))) short    bf16x8;
typedef __attribute__((ext_vector_type(4))) float    f32x4;
typedef __attribute__((ext_vector_type(4))) int      i32x4;
typedef __attribute__((ext_vector_type(4))) unsigned short u16x4;
typedef _Float16 f16x4 __attribute__((ext_vector_type(4)));
typedef __fp16   h16x2 __attribute__((ext_vector_type(2)));   // cvt_pkrtz result type

// fold 1/sqrt(dh) * log2(e) into K at write time -> scores exit MFMA in exp2 domain
#define KSCALE 0.18033688011112042f
#define LSTRIDE (24 * S_)                 // l-buffer stride per split-K half
#define ONE_EL  ((size_t)24 * S_ * DH_)   // elements per Onum partial buffer

__device__ inline unsigned short f2bf(float f) {
    union { float f; unsigned u; } v; v.f = f;
    unsigned r = v.u + 0x7FFFu + ((v.u >> 16) & 1u);   // RNE
    return (unsigned short)(r >> 16);
}

// async 16B global -> LDS (DMA; LDS dest = wave-uniform base + lane*16)
__device__ inline void async_copy16(const void* g, void* l) {
    __builtin_amdgcn_global_load_lds((const __attribute__((address_space(1))) void*)g,
                                     (__attribute__((address_space(3))) void*)l, 16, 0, 0);
}

// ---------------------------------------------------------------------------
// Fused prep: x->bf16 (blocks 0..3071), w_in transpose (3072..4799),
// w_out transpose (4800..5375). Branch is block-uniform.
__global__ __launch_bounds__(256) void prep_all(
    const float* __restrict__ x, const float* __restrict__ w_in,
    const float* __restrict__ w_out,
    unsigned short* __restrict__ xb, unsigned short* __restrict__ winT,
    unsigned short* __restrict__ woutT)
{
    __shared__ unsigned short t[32][33];
    const int gid = blockIdx.x, tid = threadIdx.x;
    if (gid < 3072) {                      // cvt: 3072*256*4 = M*D elements
        int i = gid * 256 + tid;
        f32x4 v = *(const f32x4*)(x + (size_t)i * 4);
        u16x4 o;
        o.x = f2bf(v.x); o.y = f2bf(v.y); o.z = f2bf(v.z); o.w = f2bf(v.w);
        *(u16x4*)(xb + (size_t)i * 4) = o;
        return;
    }
    const float* src; unsigned short* dst; int R, C, bx, by;
    if (gid < 4800) { int b = gid - 3072; src = w_in;  dst = winT;  R = D_; C = N3_; bx = b % 72; by = b / 72; }
    else            { int b = gid - 4800; src = w_out; dst = woutT; R = D_; C = D_;  bx = b % 24; by = b / 24; }
    int c0 = bx * 32, r0 = by * 32, tx = tid & 31, ty = tid >> 5;
#pragma unroll
    for (int j = 0; j < 4; j++)
        t[ty + j * 8][tx] = f2bf(src[(size_t)(r0 + ty + j * 8) * C + c0 + tx]);
    __syncthreads();
#pragma unroll
    for (int j = 0; j < 4; j++)
        dst[(size_t)(c0 + ty + j * 8) * R + r0 + tx] = t[tx][ty + j * 8];
}

// ---------------------------------------------------------------------------
// GEMM1: QKV projection (R4-proven best). Tile 128x96, BK=64, XOR-swizzled
// LDS rows (chunk^=(row&7)) via pre-swizzled global source; 2 barriers/iter,
// 12 iters. 1-D grid 768 = exactly 3 blocks/CU with XCD-affinity swizzle.
__global__ __launch_bounds__(256) void gemm_qkv(
    const unsigned short* __restrict__ A,
    const unsigned short* __restrict__ Bt,
    const float* __restrict__ bias,
    unsigned short* __restrict__ QK,
    unsigned short* __restrict__ Vt)
{
    __shared__ __align__(16) short Al[128 * 64];   // 16 KB
    __shared__ __align__(16) short Bl[96 * 64];    // 12 KB

    const int tid  = threadIdx.x;
    const int w    = tid >> 6;
    const int lane = tid & 63;
    const int r    = lane & 15;
    const int quad = lane >> 4;
    // swizzle: xcd = bid&7; m-tile = xcd + 8*(rest/24); n-tile = rest%24
    const int bid  = blockIdx.x;
    const int rest = bid >> 3;
    const int m0   = ((bid & 7) + 8 * (rest / 24)) * 128;
    const int n0   = (rest % 24) * 96;
    const int wm   = (w & 1) * 64;
    const int wn   = (w >> 1) * 48;
    const int K    = D_;

    f32x4 acc[4][3];
#pragma unroll
    for (int i = 0; i < 4; i++)
#pragma unroll
        for (int j = 0; j < 3; j++) acc[i][j] = f32x4{0.f, 0.f, 0.f, 0.f};

    // staging slots: slot c = tid + 256*j; row=c>>3, chunk=c&7; global chunk
    // g = chunk^(row&7) (pre-swizzle so LDS[row][chunk] = global chunk g).
    size_t ga[4], gb[3];
#pragma unroll
    for (int j = 0; j < 4; j++) {
        int c = tid + 256 * j, row = c >> 3, ch = c & 7, g = ch ^ (row & 7);
        ga[j] = (size_t)(m0 + row) * K + g * 8;
    }
#pragma unroll
    for (int j = 0; j < 3; j++) {
        int c = tid + 256 * j, row = c >> 3, ch = c & 7, g = ch ^ (row & 7);
        gb[j] = (size_t)(n0 + row) * K + g * 8;
    }

    for (int k0 = 0; k0 < K; k0 += 64) {
        __syncthreads();
#pragma unroll
        for (int j = 0; j < 4; j++)
            async_copy16(A + ga[j] + k0, &Al[(j * 256 + w * 64) * 8]);
#pragma unroll
        for (int j = 0; j < 3; j++)
            async_copy16(Bt + gb[j] + k0, &Bl[(j * 256 + w * 64) * 8]);
        __syncthreads();

#pragma unroll
        for (int kk = 0; kk < 2; kk++) {
            bf16x8 af[4], bf[3];
#pragma unroll
            for (int mi = 0; mi < 4; mi++)
                af[mi] = *(const bf16x8*)&Al[(wm + mi * 16 + r) * 64 +
                                             ((kk * 4 + quad) ^ (r & 7)) * 8];
#pragma unroll
            for (int ni = 0; ni < 3; ni++)
                bf[ni] = *(const bf16x8*)&Bl[(wn + ni * 16 + r) * 64 +
                                             ((kk * 4 + quad) ^ (r & 7)) * 8];
#pragma unroll
            for (int mi = 0; mi < 4; mi++)
#pragma unroll
                for (int ni = 0; ni < 3; ni++)
                    acc[mi][ni] = __builtin_amdgcn_mfma_f32_16x16x32_bf16(
                        af[mi], bf[ni], acc[mi][ni], 0, 0, 0);
        }
    }

    const size_t one = (size_t)B_ * H_ * S_ * DH_;
#pragma unroll
    for (int ni = 0; ni < 3; ni++) {
        int col  = n0 + wn + ni * 16 + r;        // 0..2303 (tiles never straddle parts)
        float bv = bias[col];
        int part = col / 768;                    // 0=q 1=k 2=v
        int cc   = col - part * 768;
        int h    = cc >> 6;
        int d    = cc & 63;
        if (part == 2) {
            // V^T direct: rows i=0..3 are consecutive s -> one 8B f16 pack
#pragma unroll
            for (int mi = 0; mi < 4; mi++) {
                int row0 = m0 + wm + mi * 16 + quad * 4;    // i=0; same b for i=0..3
                int b    = row0 >> 11;
                int s0   = row0 & 2047;
                u16x4 pk;
#pragma unroll
                for (int i = 0; i < 4; i++) {
                    union { _Float16 h; unsigned short s; } cv;
                    cv.h = (_Float16)(acc[mi][ni][i] + bv);
                    pk[i] = cv.s;
                }
                *(u16x4*)&Vt[(((size_t)(b * H_ + h)) * DH_ + d) * S_ + s0] = pk;
            }
        } else {
            float scl = (part == 1) ? KSCALE : 1.0f;
            unsigned short* dst = QK + (size_t)part * one;
#pragma unroll
            for (int mi = 0; mi < 4; mi++) {
#pragma unroll
                for (int i = 0; i < 4; i++) {
                    int row = m0 + wm + mi * 16 + quad * 4 + i;  // = b*S + s
                    int b   = row >> 11;
                    int s   = row & 2047;
                    dst[(((size_t)(b * H_ + h)) * S_ + s) * DH_ + d] =
                        f2bf((acc[mi][ni][i] + bv) * scl);
                }
            }
        }
    }
}

// ---------------------------------------------------------------------------
// GEMM2 FUSED with combine (R8-proven): out-projection with
// A = (O0+O1)/(l0+l1) computed during A-staging. k-tiles align with heads
// (BK=64=DH). A reg-staged (T14); B via global_load_lds DMA. Double-buffered,
// ONE barrier/iter. XOR-swizzled LDS. XCD swizzle. Grid 768.
__global__ __launch_bounds__(256) void gemm_out(
    const unsigned short* __restrict__ On,   // 2 contiguous f16 partials
    const float* __restrict__ lbuf,          // 2 x [bh*s] f32
    const unsigned short* __restrict__ Bt,   // woutT
    const float* __restrict__ bias,
    float* __restrict__ Cf)
{
    __shared__ __align__(16) short Al[2][64 * 64];   // 16 KB
    __shared__ __align__(16) short Bl[2][64 * 64];   // 16 KB

    const int tid  = threadIdx.x;
    const int w    = tid >> 6;
    const int lane = tid & 63;
    const int r    = lane & 15;
    const int quad = lane >> 4;
    const int bid  = blockIdx.x;
    const int rest = bid >> 3;
    const int m0   = ((bid & 7) + 8 * (rest / 12)) * 64;
    const int n0   = (rest % 12) * 64;
    const int wm   = (w & 1) * 32;
    const int wn   = (w >> 1) * 32;
    const int K    = D_;
    const int N    = D_;

    f32x4 acc[2][2];
#pragma unroll
    for (int i = 0; i < 2; i++)
#pragma unroll
        for (int j = 0; j < 2; j++) acc[i][j] = f32x4{0.f, 0.f, 0.f, 0.f};

    size_t abase[2]; int lrow0[2];
    size_t gb[2];
#pragma unroll
    for (int j = 0; j < 2; j++) {
        int c = tid + 256 * j, row = c >> 3, ch = c & 7, g = ch ^ (row & 7);
        int m = m0 + row, b = m >> 11, s = m & 2047;
        lrow0[j] = b * (H_ * S_) + s;
        abase[j] = (size_t)lrow0[j] * 64 + g * 8;
        gb[j] = (size_t)(n0 + row) * K + g * 8;
    }

    auto a_write = [&](int buf, const i32x4* a0, const i32x4* a1,
                       const float* l0, const float* l1) {
#pragma unroll
        for (int j = 0; j < 2; j++) {
            float inv = 1.0f / (l0[j] + l1[j]);
            const _Float16* f0 = (const _Float16*)&a0[j];
            const _Float16* f1 = (const _Float16*)&a1[j];
            unsigned short t8[8];
#pragma unroll
            for (int e = 0; e < 8; e++)
                t8[e] = f2bf(((float)f0[e] + (float)f1[e]) * inv);
            *(i32x4*)&Al[buf][(tid + 256 * j) * 8] = *(const i32x4*)t8;
        }
    };

    // prologue: stage tile 0 (head 0) into buf 0
    i32x4 a0[2], a1[2]; float l0[2], l1[2];
#pragma unroll
    for (int j = 0; j < 2; j++) {
        a0[j] = *(const i32x4*)&On[abase[j]];
        a1[j] = *(const i32x4*)&On[abase[j] + ONE_EL];
        l0[j] = lbuf[lrow0[j]];
        l1[j] = lbuf[LSTRIDE + lrow0[j]];
        async_copy16(Bt + gb[j], &Bl[0][(j * 256 + w * 64) * 8]);
    }
    a_write(0, a0, a1, l0, l1);
    __syncthreads();

    for (int it = 0; it < 12; it++) {
        const int cur = it & 1;
        if (it < 11) {
            const int itn = it + 1;
#pragma unroll
            for (int j = 0; j < 2; j++) {
                a0[j] = *(const i32x4*)&On[abase[j] + (size_t)itn * 131072];
                a1[j] = *(const i32x4*)&On[abase[j] + (size_t)itn * 131072 + ONE_EL];
                l0[j] = lbuf[lrow0[j] + itn * S_];
                l1[j] = lbuf[LSTRIDE + lrow0[j] + itn * S_];
                async_copy16(Bt + gb[j] + itn * 64, &Bl[cur ^ 1][(j * 256 + w * 64) * 8]);
            }
        }
#pragma unroll
        for (int kk = 0; kk < 2; kk++) {
            bf16x8 af[2], bf[2];
#pragma unroll
            for (int mi = 0; mi < 2; mi++)
                af[mi] = *(const bf16x8*)&Al[cur][(wm + mi * 16 + r) * 64 +
                                                  ((kk * 4 + quad) ^ (r & 7)) * 8];
#pragma unroll
            for (int ni = 0; ni < 2; ni++)
                bf[ni] = *(const bf16x8*)&Bl[cur][(wn + ni * 16 + r) * 64 +
                                                  ((kk * 4 + quad) ^ (r & 7)) * 8];
#pragma unroll
            for (int mi = 0; mi < 2; mi++)
#pragma unroll
                for (int ni = 0; ni < 2; ni++)
                    acc[mi][ni] = __builtin_amdgcn_mfma_f32_16x16x32_bf16(
                        af[mi], bf[ni], acc[mi][ni], 0, 0, 0);
        }
        if (it < 11) a_write(cur ^ 1, a0, a1, l0, l1);
        __syncthreads();
    }

#pragma unroll
    for (int ni = 0; ni < 2; ni++) {
        int col  = n0 + wn + ni * 16 + r;
        float bv = bias[col];
#pragma unroll
        for (int mi = 0; mi < 2; mi++) {
#pragma unroll
            for (int i = 0; i < 4; i++) {
                int row = m0 + wm + mi * 16 + quad * 4 + i;
                Cf[(size_t)row * N + col] = acc[mi][ni][i] + bv;
            }
        }
    }
}

// ---------------------------------------------------------------------------
// Flash attention v6 (proven best, VERBATIM — no setprio): S^T scheme +
// split-K x2 (16 kt-iters). Grid = 24*16*2 = 768 = exactly 3 blocks/CU.
// Partials: Onum f16 [half][bh][s][64] (contiguous), l f32 [half][bh*s].
__global__ __launch_bounds__(256) void attn_kernel(
    const unsigned short* __restrict__ Q,
    const unsigned short* __restrict__ K,
    const unsigned short* __restrict__ Vt,
    unsigned short* __restrict__ On,
    float* __restrict__ lbuf)
{
    __shared__ __align__(16) short Kl[64 * 64];      // [key][dh], chunk^=(row&7)
    __shared__ __align__(16) short Vl[64 * 64];      // [dh][key], chunk^=(row&7)

    const int tid  = threadIdx.x;
    const int w    = tid >> 6;
    const int lane = tid & 63;
    const int r    = lane & 15;
    const int quad = lane >> 4;
    const int xk   = r & 7;
    const int bid  = blockIdx.x;
    const int bh   = bid % 24;            // head-major -> L2 locality
    const int t2   = bid / 24;            // 0..31
    const int qb   = t2 & 15;
    const int half = t2 >> 4;
    const size_t baseQK = (size_t)bh * S_ * DH_;
    const size_t baseV  = (size_t)bh * DH_ * S_;
    const int q0   = qb * 128;
    const int kt0  = half * 16;

    bf16x8 qf[2][2];
#pragma unroll
    for (int qt = 0; qt < 2; qt++) {
        const unsigned short* qp =
            Q + baseQK + (size_t)(q0 + w * 32 + qt * 16 + r) * DH_ + quad * 8;
        qf[qt][0] = *(const bf16x8*)(qp);
        qf[qt][1] = *(const bf16x8*)(qp + 32);
    }

    f32x4 o[2][4];
    f32x4 lacc[2];
#pragma unroll
    for (int qt = 0; qt < 2; qt++) {
        lacc[qt] = f32x4{0.f, 0.f, 0.f, 0.f};
#pragma unroll
        for (int nb = 0; nb < 4; nb++) o[qt][nb] = f32x4{0.f, 0.f, 0.f, 0.f};
    }

    const f16x4 ONES = {(_Float16)1.f, (_Float16)1.f, (_Float16)1.f, (_Float16)1.f};

    const int srw = tid >> 3, schk = tid & 7;
    const unsigned short* kg = K  + baseQK + (size_t)kt0 * 4096 + tid * 8;
    const unsigned short* vg = Vt + baseV + (size_t)kt0 * 64 + (size_t)srw * S_ + schk * 8;
    const int lb = srw * 64 + (schk ^ (srw & 7)) * 8;

    i32x4 kreg[2], vreg[2];
    kreg[0] = *(const i32x4*)(kg);
    kreg[1] = *(const i32x4*)(kg + 2048);
    vreg[0] = *(const i32x4*)(vg);
    vreg[1] = *(const i32x4*)(vg + 32 * S_);

    for (int it = 0; it < 16; it++) {
        __syncthreads();
        *(i32x4*)&Kl[lb]        = kreg[0];
        *(i32x4*)&Kl[lb + 2048] = kreg[1];
        *(i32x4*)&Vl[lb]        = vreg[0];
        *(i32x4*)&Vl[lb + 2048] = vreg[1];
        __syncthreads();

        if (it != 15) {
            const unsigned short* kn = kg + (it + 1) * 4096;
            const unsigned short* vn = vg + (it + 1) * 64;
            kreg[0] = *(const i32x4*)(kn);
            kreg[1] = *(const i32x4*)(kn + 2048);
            vreg[0] = *(const i32x4*)(vn);
            vreg[1] = *(const i32x4*)(vn + 32 * S_);
        }

        // S^T = K Q^T  (exp2 domain; KSCALE folded into K)
        f32x4 sa[2][4];
#pragma unroll
        for (int qt = 0; qt < 2; qt++)
#pragma unroll
            for (int kb = 0; kb < 4; kb++) sa[qt][kb] = f32x4{0.f, 0.f, 0.f, 0.f};
#pragma unroll
        for (int t = 0; t < 2; t++)
#pragma unroll
            for (int kb = 0; kb < 4; kb++) {
                bf16x8 kf = *(const bf16x8*)&Kl[(kb * 16 + r) * 64 + ((t * 4 + quad) ^ xk) * 8];
#pragma unroll
                for (int qt = 0; qt < 2; qt++)
                    sa[qt][kb] = __builtin_amdgcn_mfma_f32_16x16x32_bf16(
                        kf, qf[qt][t], sa[qt][kb], 0, 0, 0);
            }

        // p = exp2(s) -> f16 A-frags (layout already matches; cvt_pkrtz = RTZ)
        f16x4 pf[2][4];
#pragma unroll
        for (int qt = 0; qt < 2; qt++)
#pragma unroll
            for (int kb = 0; kb < 4; kb++) {
                float p0 = __builtin_amdgcn_exp2f(sa[qt][kb][0]);
                float p1 = __builtin_amdgcn_exp2f(sa[qt][kb][1]);
                float p2 = __builtin_amdgcn_exp2f(sa[qt][kb][2]);
                float p3 = __builtin_amdgcn_exp2f(sa[qt][kb][3]);
                union { f16x4 v; h16x2 h[2]; } u;
                u.h[0] = __builtin_amdgcn_cvt_pkrtz(p0, p1);
                u.h[1] = __builtin_amdgcn_cvt_pkrtz(p2, p3);
                pf[qt][kb] = u.v;
            }

        // O += P V  and  l += P 1   (fp16 MFMA, K=16 per kb)
#pragma unroll
        for (int kb = 0; kb < 4; kb++) {
#pragma unroll
            for (int nb = 0; nb < 4; nb++) {
                f16x4 vf = *(const f16x4*)&Vl[(nb * 16 + r) * 64 +
                                              ((kb * 2 + (quad >> 1)) ^ xk) * 8 + (quad & 1) * 4];
#pragma unroll
                for (int qt = 0; qt < 2; qt++)
                    o[qt][nb] = __builtin_amdgcn_mfma_f32_16x16x16f16(
                        pf[qt][kb], vf, o[qt][nb], 0, 0, 0);
            }
#pragma unroll
            for (int qt = 0; qt < 2; qt++)
                lacc[qt] = __builtin_amdgcn_mfma_f32_16x16x16f16(
                    pf[qt][kb], ONES, lacc[qt], 0, 0, 0);
        }
    }

    // epilogue: store UN-normalized partials (f16) + l (f32)
    unsigned short* Ob = On + (size_t)half * ONE_EL;
#pragma unroll
    for (int qt = 0; qt < 2; qt++)
#pragma unroll
        for (int i = 0; i < 4; i++) {
            int s = q0 + w * 32 + qt * 16 + quad * 4 + i;
            size_t row = (size_t)bh * S_ + s;
            if (r == 0) lbuf[half * LSTRIDE + row] = lacc[qt][i];
#pragma unroll
            for (int nb = 0; nb < 4; nb++) {
                union { _Float16 h; unsigned short u; } cv;
                cv.h = (_Float16)o[qt][nb][i];
                Ob[row * 64 + nb * 16 + r] = cv.u;
            }
        }
}

// ---------------------------------------------------------------------------
extern "C" void kernel_launch(void* const* d_in, const int* in_sizes, int n_in,
                              void* d_out, int out_size, void* d_ws, size_t ws_size,
                              hipStream_t stream) {
    const float* x     = (const float*)d_in[0];
    const float* w_in  = (const float*)d_in[1];
    const float* b_in  = (const float*)d_in[2];
    const float* w_out = (const float*)d_in[3];
    const float* b_out = (const float*)d_in[4];
    float* out = (float*)d_out;
    char* ws = (char*)d_ws;

    // workspace layout (bytes), ~48.8 MB:
    //   [0,        6291456)  xb (x bf16)
    //   [6291456,  9830400)  winT (bf16)   -> lbuf (f32, 393KB) after gemm_qkv
    //   [9830400, 11010048)  woutT (bf16)
    //   [11010048,17301504)  Q  (bf16)
    //   [17301504,23592960)  K  (bf16, scaled)
    //   [23592960,29884416)  Vt (fp16, written transposed by gemm_qkv)
    //   [36175872,48758784)  Onum: 2 contiguous f16 partials (2 x 6291456)
    unsigned short* xb    = (unsigned short*)(ws);
    unsigned short* winT  = (unsigned short*)(ws + 6291456);
    unsigned short* woutT = (unsigned short*)(ws + 9830400);
    unsigned short* QKV   = (unsigned short*)(ws + 11010048);
    unsigned short* On    = (unsigned short*)(ws + 36175872);

    const size_t one = (size_t)B_ * H_ * S_ * DH_;
    unsigned short* Vtbuf = QKV + 2 * one;
    float*          lbuf  = (float*)winT;             // winT dead after gemm_qkv

    prep_all<<<5376, 256, 0, stream>>>(x, w_in, w_out, xb, winT, woutT);

    gemm_qkv<<<768, 256, 0, stream>>>(xb, winT, b_in, QKV, Vtbuf);

    attn_kernel<<<24 * 16 * 2, 256, 0, stream>>>(
        QKV, QKV + one, Vtbuf, On, lbuf);

    gemm_out<<<768, 256, 0, stream>>>(On, lbuf, woutT, b_out, out);
}